// Round 1
// 89.561 us; speedup vs baseline: 1.0311x; 1.0311x over previous
//
#include <hip/hip_runtime.h>

typedef __bf16 bf16_t;
typedef bf16_t bf16x4 __attribute__((ext_vector_type(4)));
typedef bf16_t bf16x8 __attribute__((ext_vector_type(8)));
typedef float f32x4 __attribute__((ext_vector_type(4)));
typedef float f32x16 __attribute__((ext_vector_type(16)));

namespace {
constexpr int kNH  = 16;
constexpr int kHD  = 64;
constexpr int kHID = kNH * kHD;   // 1024
constexpr int kSQ  = 2048;
constexpr int kKP  = 72;          // LDS pitch (bf16): 144B rows, b128-aligned
constexpr int oQ = 0;             // Q tile 64 x kKP (shared)
constexpr int oK = 64 * kKP;      // + wave*32*kKP (per-wave private K tile)
constexpr int kOmPitch = 68;      // epilogue float pitch
constexpr int kSmBytes = 35840;
constexpr int kKbElems = kNH * kSQ * kHD;  // 2,097,152 bf16 = 4 MB
}

// ---------------------------------------------------------------------------
// Prep pass (runs every iteration; d_ws is re-poisoned by the harness):
//  blocks [0,1024):  Kb[head][t][d] = (bf16)Kg[t][head][d]   (head-major pack)
//  blocks [1024,2048): Vb[head][tile][lane][s] = (bf16)Vg[t][head][d] in the
//    exact per-lane kappa order the PV A-fragments consume:
//      lane = h*32+m31, s = db*16+tp*8+j,
//      t = tile*32 + 4h + 16tp + (j&3) + 8*(j>>2),  d = m31 + 32*db
//  Per-head K/V footprint drops 16 MB(f32) -> 512 KB(bf16 packed): the 2 heads
//  an XCD serves become L2-resident (1 MB vs 4 MB L2), and the ~16x cross-block
//  re-reads stop streaming from L3.
// ---------------------------------------------------------------------------
__global__ __launch_bounds__(256)
void prep_kernel(const float* __restrict__ Kg, const float* __restrict__ Vg,
                 bf16_t* __restrict__ Kb, bf16_t* __restrict__ Vb) {
  const int bid = blockIdx.x;
  const int tid = threadIdx.x;
  if (bid < 1024) {
    const int o    = (bid * 256 + tid) * 8;    // bf16 out index in Kb
    const int head = o >> 17;                  // 131072 = 2048*64
    const int t    = (o >> 6) & 2047;
    const int d0   = o & 63;
    const float4 f0 = *(const float4*)(Kg + (size_t)t * kHID + head * kHD + d0);
    const float4 f1 = *(const float4*)(Kg + (size_t)t * kHID + head * kHD + d0 + 4);
    bf16x8 hk;
    hk[0] = (bf16_t)f0.x; hk[1] = (bf16_t)f0.y; hk[2] = (bf16_t)f0.z; hk[3] = (bf16_t)f0.w;
    hk[4] = (bf16_t)f1.x; hk[5] = (bf16_t)f1.y; hk[6] = (bf16_t)f1.z; hk[7] = (bf16_t)f1.w;
    *(bf16x8*)(Kb + o) = hk;
  } else {
    const int vb   = bid - 1024;               // one (head, tile) per block
    const int head = vb >> 6;
    const int tile = vb & 63;
    const int lane = tid >> 2;                 // 0..63
    const int hh   = lane >> 5;
    const int m31  = lane & 31;
    const int q    = tid & 3;
    const int db   = q >> 1, tp = q & 1;
    const int tb   = tile * 32 + 4 * hh + 16 * tp;
    const int d    = m31 + 32 * db;
    const float* src = Vg + (size_t)tb * kHID + head * kHD + d;
    bf16x8 hv;
    #pragma unroll
    for (int j = 0; j < 8; ++j)
      hv[j] = (bf16_t)src[(size_t)((j & 3) + 8 * (j >> 2)) * kHID];
    *(bf16x8*)(Vb + ((size_t)(head * 64 + tile) * 64 + lane) * 32 + (db * 16 + tp * 8)) = hv;
  }
}

// Register budget: kreg/vv staging shrank 64->32 VGPRs (bf16 prefetch regs);
// compute structure and numerics identical to the 91.9us kernel (bit-identical
// bf16 values, same MFMA order). Q frags still re-read from LDS.
__global__ __launch_bounds__(256, 2)
void fattn_kernel(const float* __restrict__ Qg, const bf16_t* __restrict__ Kb,
                  const bf16_t* __restrict__ Vb, float* __restrict__ Og) {
  __shared__ __align__(16) unsigned char smraw[kSmBytes];
  bf16_t* sm = (bf16_t*)smraw;

  const int bid  = blockIdx.x;
  const int head = bid & (kNH - 1);
  // Complementary pairing (R11): CU c hosts blocks b and b+256 -> per-CU work
  // = 66 tiles, constant.
  const int idx16 = bid >> 4;                                // 0..31
  const int mblk  = (bid < 256) ? (31 - idx16) : (idx16 - 16);
  const int m0   = mblk * 64;
  const int mtk  = 2 * mblk + 1;      // last 32-key tile index

  const int tid  = threadIdx.x;
  const int wave = tid >> 6;          // key-group: tiles jt == wave (mod 4)
  const int lane = tid & 63;
  const int h    = lane >> 5;
  const int m31  = lane & 31;

  bf16_t* qs = sm + oQ;
  bf16_t* ks = sm + oK + wave * 32 * kKP;

  const float kQScale = 0.125f * 1.44269504088896340736f;  // 1/sqrt(64)*log2(e)

  // ---- stage Q tile (64 rows) cooperatively; one prologue barrier ----
  #pragma unroll
  for (int i = 0; i < 4; ++i) {
    const int idx = tid + 256 * i;          // 1024 float4s
    const int row = idx >> 4;
    const int c4  = (idx & 15) * 4;
    const float4 f = *(const float4*)(Qg + (size_t)(m0 + row) * kHID + head * kHD + c4);
    bf16x4 hq;
    hq[0] = (bf16_t)(f.x * kQScale); hq[1] = (bf16_t)(f.y * kQScale);
    hq[2] = (bf16_t)(f.z * kQScale); hq[3] = (bf16_t)(f.w * kQScale);
    *(bf16x4*)(qs + row * kKP + c4) = hq;
  }
  __syncthreads();

  // O^T accumulators: Oa[db][qh] (AGPRs); l partials per q-half
  f32x16 Oa00, Oa10, Oa01, Oa11;
  #pragma unroll
  for (int r = 0; r < 16; ++r) { Oa00[r] = 0.f; Oa10[r] = 0.f; Oa01[r] = 0.f; Oa11[r] = 0.f; }
  float lacc0 = 0.f, lacc1 = 0.f;

  // K tile load: lane covers row lane>>1, 32-col half (lane&1); 64B/lane
  const int krow = lane >> 1;
  const int kcol = (lane & 1) * 32;
  const bf16_t* kbase = Kb + (size_t)head * (kSQ * kHD) + (size_t)krow * kHD + kcol;
  // V tile load: pre-gathered kappa order; 64B/lane, wave reads 4KB contiguous
  const bf16_t* vbase = Vb + ((size_t)head * 64 * 64 + lane) * 32;

  bf16x8 kreg[4];   // K prefetch, spans backedge
  bf16x8 vreg[4];   // V prefetch (= PV A-frags directly), spans backedge

  if (wave <= mtk) {
    #pragma unroll
    for (int i = 0; i < 4; ++i)
      kreg[i] = *(const bf16x8*)(kbase + (size_t)(wave * 32) * kHD + 8 * i);
    #pragma unroll
    for (int i = 0; i < 4; ++i)
      vreg[i] = *(const bf16x8*)(vbase + (size_t)wave * 2048 + 8 * i);
  }

  for (int jt = wave; jt <= mtk; jt += 4) {
    const int kv0 = jt * 32;

    // a) kreg (arrived last iteration) -> private LDS K tile; no cvt needed
    #pragma unroll
    for (int i = 0; i < 4; ++i)
      *(bf16x8*)(ks + krow * kKP + kcol + 8 * i) = kreg[i];

    // b) V frags are the prefetch regs directly (WAR vs prefetch by order)
    bf16x8 va0 = vreg[0], va1 = vreg[1], va2 = vreg[2], va3 = vreg[3];

    // c) prefetch next K,V tile (full iteration of cover)
    if (jt + 4 <= mtk) {
      const int kn = (jt + 4) * 32;
      #pragma unroll
      for (int i = 0; i < 4; ++i)
        kreg[i] = *(const bf16x8*)(kbase + (size_t)kn * kHD + 8 * i);
      #pragma unroll
      for (int i = 0; i < 4; ++i)
        vreg[i] = *(const bf16x8*)(vbase + (size_t)(jt + 4) * 2048 + 8 * i);
    }

    // d) q-half 0 (skip if this key tile is entirely above the diagonal)
    if (kv0 <= m0) {
      f32x16 cs;
      #pragma unroll
      for (int r = 0; r < 16; ++r) cs[r] = 0.f;
      #pragma unroll
      for (int t = 0; t < 4; ++t) {
        bf16x8 af = *(const bf16x8*)(ks + m31 * kKP + 16 * t + 8 * h);
        bf16x8 qf = *(const bf16x8*)(qs + m31 * kKP + 16 * t + 8 * h);
        cs = __builtin_amdgcn_mfma_f32_32x32x16_bf16(af, qf, cs, 0, 0, 0);
      }
      float p[16];
      if (kv0 == m0) {   // diagonal subtile
        #pragma unroll
        for (int r = 0; r < 16; ++r) {
          const int kr = (r & 3) + 8 * (r >> 2) + 4 * h;
          const float e = __builtin_amdgcn_exp2f(cs[r]);
          p[r] = (kr <= m31) ? e : 0.f;
          lacc0 += p[r];
        }
      } else {
        #pragma unroll
        for (int r = 0; r < 16; ++r) { p[r] = __builtin_amdgcn_exp2f(cs[r]); lacc0 += p[r]; }
      }
      bf16x8 pb0, pb1;
      #pragma unroll
      for (int j = 0; j < 8; ++j) { pb0[j] = (bf16_t)p[j]; pb1[j] = (bf16_t)p[8 + j]; }
      Oa00 = __builtin_amdgcn_mfma_f32_32x32x16_bf16(va0, pb0, Oa00, 0, 0, 0);
      Oa10 = __builtin_amdgcn_mfma_f32_32x32x16_bf16(va2, pb0, Oa10, 0, 0, 0);
      Oa00 = __builtin_amdgcn_mfma_f32_32x32x16_bf16(va1, pb1, Oa00, 0, 0, 0);
      Oa10 = __builtin_amdgcn_mfma_f32_32x32x16_bf16(va3, pb1, Oa10, 0, 0, 0);
    }

    // e) q-half 1 (kv0 <= m0+32 always holds)
    {
      f32x16 cs;
      #pragma unroll
      for (int r = 0; r < 16; ++r) cs[r] = 0.f;
      #pragma unroll
      for (int t = 0; t < 4; ++t) {
        bf16x8 af = *(const bf16x8*)(ks + m31 * kKP + 16 * t + 8 * h);
        bf16x8 qf = *(const bf16x8*)(qs + (32 + m31) * kKP + 16 * t + 8 * h);
        cs = __builtin_amdgcn_mfma_f32_32x32x16_bf16(af, qf, cs, 0, 0, 0);
      }
      float p[16];
      if (kv0 == m0 + 32) {   // diagonal subtile
        #pragma unroll
        for (int r = 0; r < 16; ++r) {
          const int kr = (r & 3) + 8 * (r >> 2) + 4 * h;
          const float e = __builtin_amdgcn_exp2f(cs[r]);
          p[r] = (kr <= m31) ? e : 0.f;
          lacc1 += p[r];
        }
      } else {
        #pragma unroll
        for (int r = 0; r < 16; ++r) { p[r] = __builtin_amdgcn_exp2f(cs[r]); lacc1 += p[r]; }
      }
      bf16x8 pb0, pb1;
      #pragma unroll
      for (int j = 0; j < 8; ++j) { pb0[j] = (bf16_t)p[j]; pb1[j] = (bf16_t)p[8 + j]; }
      Oa01 = __builtin_amdgcn_mfma_f32_32x32x16_bf16(va0, pb0, Oa01, 0, 0, 0);
      Oa11 = __builtin_amdgcn_mfma_f32_32x32x16_bf16(va2, pb0, Oa11, 0, 0, 0);
      Oa01 = __builtin_amdgcn_mfma_f32_32x32x16_bf16(va1, pb1, Oa01, 0, 0, 0);
      Oa11 = __builtin_amdgcn_mfma_f32_32x32x16_bf16(va3, pb1, Oa11, 0, 0, 0);
    }
  }

  // ---- epilogue: two passes (one per q-half), 4-way additive merge via LDS ----
  float* fv   = (float*)smraw;
  float* Om   = fv + wave * 32 * kOmPitch;   // per-wave 32 rows x 68
  float* larr = fv + 4 * 32 * kOmPitch;      // 4 waves x 64 l-partials

  #pragma unroll
  for (int qh = 0; qh < 2; ++qh) {
    __syncthreads();   // pass0: main-loop LDS dead; pass1: pass0 reads done
    {
      const f32x16& A0 = qh ? Oa01 : Oa00;   // d 0..31
      const f32x16& A1 = qh ? Oa11 : Oa10;   // d 32..63
      #pragma unroll
      for (int q = 0; q < 4; ++q) {
        f32x4 v0, v1;
        #pragma unroll
        for (int e = 0; e < 4; ++e) { v0[e] = A0[4 * q + e]; v1[e] = A1[4 * q + e]; }
        *(f32x4*)(Om + (size_t)m31 * kOmPitch + 8 * q + 4 * h)      = v0;
        *(f32x4*)(Om + (size_t)m31 * kOmPitch + 32 + 8 * q + 4 * h) = v1;
      }
      larr[wave * 64 + lane] = qh ? lacc1 : lacc0;
    }
    __syncthreads();
    #pragma unroll
    for (int i = 0; i < 2; ++i) {
      const int idx = tid + 256 * i;        // 512 float4s: 32 rows x 16 cols
      const int row = idx >> 4;
      const int c4  = (idx & 15) * 4;
      float l = 0.f;
      #pragma unroll
      for (int w = 0; w < 4; ++w)
        l += larr[w * 64 + row] + larr[w * 64 + 32 + row];
      const float inv = 1.f / l;
      f32x4 o;
      #pragma unroll
      for (int e = 0; e < 4; ++e) o[e] = 0.f;
      #pragma unroll
      for (int w = 0; w < 4; ++w) {
        const f32x4 a = *(const f32x4*)(fv + w * 32 * kOmPitch + (size_t)row * kOmPitch + c4);
        #pragma unroll
        for (int e = 0; e < 4; ++e) o[e] += a[e];
      }
      #pragma unroll
      for (int e = 0; e < 4; ++e) o[e] *= inv;
      *(f32x4*)(Og + (size_t)(m0 + 32 * qh + row) * kHID + head * kHD + c4) = o;
    }
  }
}

extern "C" void kernel_launch(void* const* d_in, const int* in_sizes, int n_in,
                              void* d_out, int out_size, void* d_ws, size_t ws_size,
                              hipStream_t stream) {
  (void)in_sizes; (void)n_in; (void)ws_size; (void)out_size;
  const float* Q = (const float*)d_in[0];
  const float* K = (const float*)d_in[1];
  const float* V = (const float*)d_in[2];
  float* O = (float*)d_out;
  bf16_t* Kb = (bf16_t*)d_ws;            // 4 MB: [head][t][d] bf16
  bf16_t* Vb = Kb + kKbElems;            // 4 MB: pre-gathered kappa order
  hipLaunchKernelGGL(prep_kernel, dim3(2048), dim3(256), 0, stream, K, V, Kb, Vb);
  dim3 grid(512);    // 16 heads x 32 q-tiles (64 rows), complementary-paired
  dim3 block(256);   // 4 waves = 4 key-groups, barrier-free main loop
  hipLaunchKernelGGL(fattn_kernel, grid, block, 0, stream, Q, Kb, Vb, O);
}